// Round 15
// baseline (19799.976 us; speedup 1.0000x reference)
//
#include <hip/hip_runtime.h>

namespace {
constexpr int TT  = 2048;
constexpr int NBL = 64;                 // blocks per layer
constexpr size_t YSZ = (size_t)32 * TT * 512;
constexpr size_t HFO = YSZ;
constexpr size_t CFO = YSZ + (size_t)2 * 32 * 512;
// LDS map (157760 B)
constexpr int O_WLO  = 65536;           // W lo plane (hi at 0); 32 rows x 2048 B
constexpr int O_GA   = 131072;          // 8 tiles x 272 floats
constexpr int O_XGB  = 139776;          // 2 slots x 8704 B
constexpr int O_HOUT = 157184;          // 32 x 8 shorts
constexpr int O_LF   = 157696;          // 16 ints
constexpr int TILE_F = 272;
constexpr int LF_GA = 0, LF_XF = 4, LF_XC = 8;
}

typedef float f32x4 __attribute__((ext_vector_type(4)));
typedef short s16x8 __attribute__((ext_vector_type(8)));
typedef int   i32x4 __attribute__((ext_vector_type(4)));

__device__ __forceinline__ float sigf(float v)  { return 1.0f / (1.0f + __expf(-v)); }
__device__ __forceinline__ float tanh_(float v) { return 1.0f - 2.0f / (__expf(2.0f * v) + 1.0f); }
__device__ __forceinline__ short f2bf(float v) {
  unsigned u = __float_as_uint(v);
  u += 0x7FFFu + ((u >> 16) & 1u);
  return (short)(u >> 16);
}
__device__ __forceinline__ float bf2f(short h) {
  return __uint_as_float(((unsigned)(unsigned short)h) << 16);
}
__device__ __forceinline__ s16x8 cvt8hi(const f32x4& p, const f32x4& q) {
  s16x8 r;
  r[0] = f2bf(p.x); r[1] = f2bf(p.y); r[2] = f2bf(p.z); r[3] = f2bf(p.w);
  r[4] = f2bf(q.x); r[5] = f2bf(q.y); r[6] = f2bf(q.z); r[7] = f2bf(q.w);
  return r;
}
// coherent 16B packet ops (sc1: bypass L1/L2 -> shared coherence point)
__device__ __forceinline__ i32x4 ld_pkt(const void* p) {
  i32x4 r;
  asm volatile("global_load_dwordx4 %0, %1, off sc1" : "=v"(r) : "v"(p) : "memory");
  return r;
}
__device__ __forceinline__ void st_pkt(void* p, i32x4 v) {
  asm volatile("global_store_dwordx4 %0, %1, off sc1" :: "v"(p), "v"(v) : "memory");
}
__device__ __forceinline__ s16x8 mk_bh(i32x4 a, i32x4 b) {
  i32x4 t;
  t[0] = a[0]; t[1] = a[1]; t[2] = b[0]; t[3] = b[1];
  return __builtin_bit_cast(s16x8, t);
}
__device__ __forceinline__ void st_flag(int* p, int v) {
  __hip_atomic_store(p, v, __ATOMIC_RELAXED, __HIP_MEMORY_SCOPE_AGENT);
}
__device__ __forceinline__ void poll_ge(const int* f, int need) {
  while (__hip_atomic_load(f, __ATOMIC_RELAXED, __HIP_MEMORY_SCOPE_AGENT) < need)
    __builtin_amdgcn_s_sleep(1);
}
__device__ __forceinline__ void lspin_ge(int* p, int need) {
  while (__hip_atomic_load(p, __ATOMIC_ACQUIRE, __HIP_MEMORY_SCOPE_WORKGROUP) < need)
    __builtin_amdgcn_s_sleep(0);
  __builtin_amdgcn_sched_barrier(0);
}
__device__ __forceinline__ void lset(int* p, int v) {
  __hip_atomic_store(p, v, __ATOMIC_RELEASE, __HIP_MEMORY_SCOPE_WORKGROUP);
}

#define VMCNT0() do { asm volatile("s_waitcnt vmcnt(0)" ::: "memory"); __builtin_amdgcn_sched_barrier(0); } while (0)
#define LGKM0()  do { asm volatile("s_waitcnt lgkmcnt(0)" ::: "memory"); __builtin_amdgcn_sched_barrier(0); } while (0)

#define MFMA __builtin_amdgcn_mfma_f32_16x16x32_bf16

__global__ __launch_bounds__(512)
void lstm_persist(
    const float* __restrict__ x,
    const float* __restrict__ Wih0, const float* __restrict__ Whh0,
    const float* __restrict__ bih0, const float* __restrict__ bhh0,
    const float* __restrict__ Wih1, const float* __restrict__ Whh1,
    const float* __restrict__ bih1, const float* __restrict__ bhh1,
    const float* __restrict__ h0c, const float* __restrict__ c0c,
    float* __restrict__ out,
    char* __restrict__ ring0, char* __restrict__ ring1, int* __restrict__ flags1)
{
  __shared__ __align__(16) char LDS[157760];
  char* Whi = LDS;                       // swizzled: (row<<11) + ((k<<1) ^ ((row&15)<<4))
  char* Wlo = LDS + O_WLO;
  float* gAp = (float*)(LDS + O_GA);
  float* xgp = (float*)(LDS + O_XGB);
  int* lf = (int*)(LDS + O_LF);

  const int tid   = (int)threadIdx.x;
  const int lane  = tid & 63;
  const int w     = tid >> 6;            // 0-3: A (recurrent+cell); 4-7: B (ff producer)
  const int layer = (int)(blockIdx.x >> 6);
  const int lb    = (int)(blockIdx.x & (NBL - 1));
  const int j0    = lb << 3;             // 8 columns per block
  const bool isA  = (w < 4);

  const float* Wih = layer ? Wih1 : Wih0;
  const float* Whh = layer ? Whh1 : Whh0;
  const float* bih = layer ? bih1 : bih0;
  const float* bhh = layer ? bhh1 : bhh0;
  char* rO = layer ? ring1 : ring0;      // own-layer packet ring
  const int rmask = layer ? 3 : 7;       // slots: L0=8 (feeds L1-B), L1=4

  // ---- prologue: W' -> bf16 hi/lo LDS planes ----
  for (int idx = tid; idx < 32 * 1024; idx += 512) {
    const int row = idx >> 10;           // g*8 + jj
    const int k   = idx & 1023;          // 0-511 Wih, 512-1023 Whh
    const int rg  = ((row >> 3) << 9) + j0 + (row & 7);
    const float vv = (k < 512) ? Wih[(rg << 9) + k] : Whh[(rg << 9) + (k - 512)];
    const short h = f2bf(vv);
    const short l = f2bf(vv - bf2f(h));
    const int byte = (row << 11) + ((k << 1) ^ ((row & 15) << 4));
    *(short*)(Whi + byte) = h;
    *(short*)(Wlo + byte) = l;
  }
  // ---- prologue: h(-1) packets for own cols (seq=1); ring memset'd to 0 ----
  if (w == 0) {
    const int b = lane >> 1, g = lane & 1;
    const float* hp = h0c + layer * 512 + j0 + (g << 2);
    i32x4 pkt;
    pkt[0] = (int)(unsigned short)f2bf(hp[0]) | ((int)(unsigned short)f2bf(hp[1]) << 16);
    pkt[1] = (int)(unsigned short)f2bf(hp[2]) | ((int)(unsigned short)f2bf(hp[3]) << 16);
    pkt[2] = 1; pkt[3] = 0;
    st_pkt(rO + (rmask << 16) + (b << 11) + (lb << 5) + (g << 4), pkt);
  }
  if (tid == 0) {
#pragma unroll
    for (int i = 0; i < 16; ++i) lf[i] = 0;
  }
  float creg = 0.0f;
  float bias_[4] = {0.f, 0.f, 0.f, 0.f};
  int jjC = 0, bC = 0;
  if (isA) {                             // 256 A-threads = 256 cells
    jjC = tid >> 5;
    bC  = tid & 31;
    creg = c0c[layer * 512 + j0 + jjC];
#pragma unroll
    for (int g = 0; g < 4; ++g) bias_[g] = bih[(g << 9) + j0 + jjC] + bhh[(g << 9) + j0 + jjC];
  }
  LGKM0();
  __builtin_amdgcn_s_barrier();          // only barrier (W + lf ready)
  __builtin_amdgcn_sched_barrier(0);

  const int kg = lane >> 4;              // 0..3

  if (isA) {
    // ================= A: recurrent half (W cols 512+), cell =================
    const int bg = w & 1, kh = w >> 1;
    const int b_ld = (bg << 4) + (lane & 15);
#pragma unroll 1
    for (int s = 0; s < TT; ++s) {
      // ---- self-validating data poll: h(s-1) packets, seq == s+1 ----
      const char* hb = rO + ((((s - 1) & rmask)) << 16) + (b_ld << 11) + (kh << 10) + (kg << 5);
      const int want = s + 1;
      i32x4 gr[16];
      while (true) {
#pragma unroll
        for (int ks = 0; ks < 8; ++ks) {
          gr[2 * ks]     = ld_pkt(hb + (ks << 7));
          gr[2 * ks + 1] = ld_pkt(hb + (ks << 7) + 16);
        }
        VMCNT0();
        int bad = 0;
#pragma unroll
        for (int i = 0; i < 16; ++i) bad |= (gr[i][2] != want) ? 1 : 0;
        if (!__any(bad)) break;
      }
      f32x4 acc[2][2];
#pragma unroll
      for (int rg = 0; rg < 2; ++rg)
#pragma unroll
        for (int p = 0; p < 2; ++p) acc[rg][p] = (f32x4){0.f, 0.f, 0.f, 0.f};
#pragma unroll
      for (int ks = 0; ks < 8; ++ks) {
        const s16x8 bh = mk_bh(gr[2 * ks], gr[2 * ks + 1]);
#pragma unroll
        for (int rg = 0; rg < 2; ++rg) {
          const int wrow = (rg << 4) + (lane & 15);
          const int wk = 512 + (kh << 8) + (ks << 5) + (kg << 3);
          const int wb = (wrow << 11) + ((wk << 1) ^ ((wrow & 15) << 4));
          acc[rg][ks & 1] = MFMA(*(const s16x8*)(Whi + wb), bh, acc[rg][ks & 1], 0, 0, 0);
          acc[rg][ks & 1] = MFMA(*(const s16x8*)(Wlo + wb), bh, acc[rg][ks & 1], 0, 0, 0);
        }
      }
#pragma unroll
      for (int rg = 0; rg < 2; ++rg) {
        const f32x4 c = acc[rg][0] + acc[rg][1];
        float* tp = gAp + ((kh << 2) + (rg << 1) + bg) * TILE_F + (kg << 2) * 17 + (lane & 15);
#pragma unroll
        for (int r = 0; r < 4; ++r) tp[r * 17] = c[r];
      }
      LGKM0();
      lset(&lf[LF_GA + w], s + 1);
#pragma unroll
      for (int i = 0; i < 4; ++i) lspin_ge(&lf[LF_GA + i], s + 1);
#pragma unroll
      for (int i = 0; i < 4; ++i) lspin_ge(&lf[LF_XF + i], s + 1);
      // ---- cell ----
      const float* xgs = xgp + (s & 1) * 2176;
      float gv[4];
#pragma unroll
      for (int g = 0; g < 4; ++g) {
        const int row = (g << 3) + jjC;
        const int base = (((row >> 4) << 1) + (bC >> 4)) * TILE_F + (row & 15) * 17 + (bC & 15);
        gv[g] = gAp[base] + gAp[base + 4 * TILE_F] + xgs[base] + xgs[base + 4 * TILE_F] + bias_[g];
      }
      const float cn = sigf(gv[1]) * creg + sigf(gv[0]) * tanh_(gv[2]);
      const float hn = sigf(gv[3]) * tanh_(cn);
      creg = cn;
      if (layer == 1) out[((size_t)((bC << 11) + s) << 9) + j0 + jjC] = hn;
      if (s == TT - 1) out[HFO + (size_t)(((layer << 5) + bC) << 9) + j0 + jjC] = hn;
      *(short*)(LDS + O_HOUT + (bC << 4) + (jjC << 1)) = f2bf(hn);
      LGKM0();
      lset(&lf[LF_XC + w], s + 1);       // cell done (hout written, xg consumed)
      if (w == 0) {
        lspin_ge(&lf[LF_XC + 1], s + 1);
        lspin_ge(&lf[LF_XC + 2], s + 1);
        lspin_ge(&lf[LF_XC + 3], s + 1);
        if (layer == 0 && s >= 8) poll_ge(flags1 + lane, s - 7);  // L1-A past step s-7
        const int b = lane >> 1, g = lane & 1;
        i32x4 pkt;
        pkt[0] = *(const int*)(LDS + O_HOUT + (b << 4) + (g << 3));
        pkt[1] = *(const int*)(LDS + O_HOUT + (b << 4) + (g << 3) + 4);
        pkt[2] = s + 2; pkt[3] = 0;
        st_pkt(rO + ((s & rmask) << 16) + (b << 11) + (lb << 5) + (g << 4), pkt);
        // fire-and-forget: no drain, no flag; packets self-validate
        if (layer == 1 && lane == 0) st_flag(flags1 + lb, s + 1);  // backpressure progress
      }
    }
    out[CFO + (size_t)(((layer << 5) + bC) << 9) + j0 + jjC] = creg;
  } else {
    // ================= B: feed-forward half (W cols 0-511), runs ahead =================
    const int v = w - 4;
    const int bg = v & 1, kh = v >> 1;
    const int b_ld = (bg << 4) + (lane & 15);
#pragma unroll 1
    for (int t = 0; t < TT; ++t) {
#pragma unroll
      for (int i = 0; i < 4; ++i) lspin_ge(&lf[LF_XC + i], t - 1);  // xg slot t&1 free
      f32x4 acc[2][2];
#pragma unroll
      for (int rg = 0; rg < 2; ++rg)
#pragma unroll
        for (int p = 0; p < 2; ++p) acc[rg][p] = (f32x4){0.f, 0.f, 0.f, 0.f};
      if (layer == 0) {
        // x[t] fp32 via L2-cacheable loads, cvt to bf16-hi in-register
        const int colb = (kh << 8) + (kg << 3);
#pragma unroll 1
        for (int round = 0; round < 2; ++round) {
          f32x4 xr[8];
#pragma unroll
          for (int i = 0; i < 8; ++i) {
            const int ks = (round << 2) + (i >> 1);
            const int col = colb + (ks << 5) + ((i & 1) << 2);
            xr[i] = *(const f32x4*)(x + ((size_t)((b_ld << 11) + t) << 9) + col);
          }
#pragma unroll
          for (int sl = 0; sl < 4; ++sl) {
            const int ks = (round << 2) + sl;
            const s16x8 bh = cvt8hi(xr[sl << 1], xr[(sl << 1) + 1]);
#pragma unroll
            for (int rg = 0; rg < 2; ++rg) {
              const int wrow = (rg << 4) + (lane & 15);
              const int wk = (kh << 8) + (ks << 5) + (kg << 3);
              const int wb = (wrow << 11) + ((wk << 1) ^ ((wrow & 15) << 4));
              acc[rg][ks & 1] = MFMA(*(const s16x8*)(Whi + wb), bh, acc[rg][ks & 1], 0, 0, 0);
              acc[rg][ks & 1] = MFMA(*(const s16x8*)(Wlo + wb), bh, acc[rg][ks & 1], 0, 0, 0);
            }
          }
        }
      } else {
        // y0(t) packets from L0 ring (8 slots), seq == t+2
        const char* yb = ring0 + (((t & 7)) << 16) + (b_ld << 11) + (kh << 10) + (kg << 5);
        const int want = t + 2;
        i32x4 gr[16];
        while (true) {
#pragma unroll
          for (int ks = 0; ks < 8; ++ks) {
            gr[2 * ks]     = ld_pkt(yb + (ks << 7));
            gr[2 * ks + 1] = ld_pkt(yb + (ks << 7) + 16);
          }
          VMCNT0();
          int bad = 0;
#pragma unroll
          for (int i = 0; i < 16; ++i) bad |= (gr[i][2] != want) ? 1 : 0;
          if (!__any(bad)) break;
        }
#pragma unroll
        for (int ks = 0; ks < 8; ++ks) {
          const s16x8 bh = mk_bh(gr[2 * ks], gr[2 * ks + 1]);
#pragma unroll
          for (int rg = 0; rg < 2; ++rg) {
            const int wrow = (rg << 4) + (lane & 15);
            const int wk = (kh << 8) + (ks << 5) + (kg << 3);
            const int wb = (wrow << 11) + ((wk << 1) ^ ((wrow & 15) << 4));
            acc[rg][ks & 1] = MFMA(*(const s16x8*)(Whi + wb), bh, acc[rg][ks & 1], 0, 0, 0);
            acc[rg][ks & 1] = MFMA(*(const s16x8*)(Wlo + wb), bh, acc[rg][ks & 1], 0, 0, 0);
          }
        }
      }
      float* xps = xgp + (t & 1) * 2176;
#pragma unroll
      for (int rg = 0; rg < 2; ++rg) {
        const f32x4 c = acc[rg][0] + acc[rg][1];
        float* tp = xps + ((kh << 2) + (rg << 1) + bg) * TILE_F + (kg << 2) * 17 + (lane & 15);
#pragma unroll
        for (int r = 0; r < 4; ++r) tp[r * 17] = c[r];
      }
      LGKM0();
      lset(&lf[LF_XF + v], t + 1);       // xg(t) published
    }
  }
}

extern "C" void kernel_launch(void* const* d_in, const int* in_sizes, int n_in,
                              void* d_out, int out_size, void* d_ws, size_t ws_size,
                              hipStream_t stream) {
  (void)in_sizes; (void)n_in; (void)out_size; (void)ws_size;
  const float* x    = (const float*)d_in[0];
  const float* Wih0 = (const float*)d_in[1];
  const float* Whh0 = (const float*)d_in[2];
  const float* bih0 = (const float*)d_in[3];
  const float* bhh0 = (const float*)d_in[4];
  const float* Wih1 = (const float*)d_in[5];
  const float* Whh1 = (const float*)d_in[6];
  const float* bih1 = (const float*)d_in[7];
  const float* bhh1 = (const float*)d_in[8];
  const float* h0   = (const float*)d_in[9];
  const float* c0   = (const float*)d_in[10];

  float* out = (float*)d_out;
  // ring packet: [slot][b:32][p:64][g:2] x 16B -> 64 KB/slot
  char* ring0 = (char*)d_ws;                             // 8 slots = 512 KB
  char* ring1 = (char*)d_ws + (512 << 10);               // 4 slots = 256 KB
  int*  flags1 = (int*)((char*)d_ws + (768 << 10));      // 64 ints (backpressure)

  // rings + flags must be zeroed every call: packet seq==0 means "invalid",
  // and graph replays don't re-poison d_ws (stale seq from a previous run
  // would otherwise validate immediately).
  hipMemsetAsync(d_ws, 0, (768 << 10) + 4096, stream);

  hipLaunchKernelGGL(lstm_persist, dim3(2 * NBL), dim3(512), 0, stream,
                     x, Wih0, Whh0, bih0, bhh0, Wih1, Whh1, bih1, bhh1,
                     h0, c0, out, ring0, ring1, flags1);
}